// Round 10
// baseline (133.068 us; speedup 1.0000x reference)
//
#include <hip/hip_runtime.h>
#include <hip/hip_bf16.h>

#define NLIG 1024
#define NREC 4096
#define NTOT 5120
#define ELIG 8192
#define ETOT 40960
#define TPAD 1092      // 17*64 padded +4

typedef __bf16 bf16x8 __attribute__((ext_vector_type(8)));
typedef float f32x4 __attribute__((ext_vector_type(4)));

struct Params {
  const float *lig_x, *rec_x, *lig_e, *rec_e;
  const int *lig_src, *lig_dst, *rec_src, *rec_dst;
  const float *nW[2], *nb[2], *eW[2], *eb[2], *hW[2], *hb[2], *g0[2], *b0[2];
  const float *efW[2], *efb[2], *convb[2], *outW[2], *outb[2], *lng[2], *lnb[2];
  float *msgvA, *msgvB, *prev0, *eh;
  __bf16 *Wp, *oWp;
  unsigned short *sbkt, *dbkt;      // [320][2048] local edge ids
  int *sbg, *scg, *dbg, *dcg;       // [320][16] bucket base/count (src,dst)
  float *out;
};

__device__ __forceinline__ float lrelu(float v){ return v > 0.f ? v : 0.01f * v; }

__device__ __forceinline__ float wsum(float v){
  #pragma unroll
  for (int off = 32; off > 0; off >>= 1) v += __shfl_xor(v, off, 64);
  return v;
}

// Window decomposition: block -> 16 nodes of one graph + that graph's edge range.
__device__ __forceinline__ void window(int bid, int& side, int& r0, int& gr0,
                                       int& ebase, int& ecnt, int& egbase,
                                       const int*& srcArr, const int*& dstArr,
                                       const Params& p){
  if (bid < 64){
    side = 0; int b = bid >> 2, w = bid & 3;
    r0 = b*64 + w*16; gr0 = r0; ebase = b*512; ecnt = 512; egbase = ebase;
    srcArr = p.lig_src; dstArr = p.lig_dst;
  } else {
    side = 1; int g = bid - 64; int b = g >> 4, w = g & 15;
    r0 = b*256 + w*16; gr0 = NLIG + r0; ebase = b*2048; ecnt = 2048; egbase = ELIG + ebase;
    srcArr = p.rec_src; dstArr = p.rec_dst;
  }
}

// ---- K_front (320 x 1024): bucketing + node-emb/LN0 + edge-emb + pack W
//      + tmat(layer0, raw efW) + msg(layer0) -> msgvA.  No cross-block reads.
__global__ __launch_bounds__(1024, 8) void k_front(Params p){
  union EmbT {
    struct { float nwl[40*64], hwl[64*64], sx[16][40], st[16][64]; } e;
    __bf16 Tl[16][TPAD];
  };
  __shared__ EmbT su;
  __shared__ float sW[256], sb[16];
  __shared__ __bf16 albf[16][64];
  __shared__ unsigned short slist[2048];
  __shared__ int scnt[16], sbase[16], scur[16], dcnt[16], dbase[16], dcur[16];
  __shared__ int sTot;

  const int tid = threadIdx.x, bid = blockIdx.x;
  const int lane = tid & 63, wid = tid >> 6;
  const int gtid = bid*1024 + tid;

  int side, r0, gr0, ebase, ecnt, egbase;
  const int *srcArr, *dstArr;
  window(bid, side, r0, gr0, ebase, ecnt, egbase, srcArr, dstArr, p);
  const int nin = side ? 40 : 32;

  if (tid < 256) sW[tid] = p.eW[side][tid];
  if (tid < 16){ sb[tid] = p.eb[side][tid]; scnt[tid] = 0; dcnt[tid] = 0; }
  for (int i = tid; i < nin*64; i += 1024) su.e.nwl[i] = p.nW[side][i];
  for (int i = tid; i < 4096; i += 1024) su.e.hwl[i] = p.hW[side][i];
  if (gtid < 16) p.out[gtid] = 0.f;

  // pack W_all = [efW 0..15 | efb] into MFMA B-fragment order (used layers 1,2)
  if (gtid < 52224){
    int l  = gtid & 63;
    int t2 = gtid >> 6;
    int kk = t2 & 1;
    int t3 = t2 >> 1;
    int ct = t3 % 68;
    int sl = t3 / 68;            // side*3 + layer
    int sd = sl / 3, ly = sl % 3;
    int ocol = ct*16 + (l & 15);
    int kslot = ocol >> 6, oo = ocol & 63;
    const float* src = (kslot < 16)
        ? (p.efW[sd] + (size_t)ly*16*4096 + (size_t)kslot*4096)
        : (p.efb[sd] + (size_t)ly*4096);
    bf16x8 w;
    #pragma unroll
    for (int j = 0; j < 8; j++){
      int i = kk*32 + (l >> 4)*8 + j;
      w[j] = (__bf16)src[i*64 + oo];
    }
    ((bf16x8*)p.Wp)[(size_t)sl*68*2*64 + (ct*2 + kk)*64 + l] = w;
  } else if (gtid < 52224 + 3072){
    // pack outW (3 layers x 2 sides) into B-fragment order
    int id2 = gtid - 52224;
    int l = id2 & 63;
    int t2 = id2 >> 6;
    int kk = t2 & 1;
    int ct = (t2 >> 1) & 3;
    int sl = t2 >> 3;            // side*3 + layer
    int sd = sl / 3, ly = sl % 3;
    const float* src = p.outW[sd] + (size_t)ly*4096;
    bf16x8 w;
    #pragma unroll
    for (int j = 0; j < 8; j++){
      int i = kk*32 + (l >> 4)*8 + j;
      w[j] = (__bf16)src[i*64 + ct*16 + (l & 15)];
    }
    ((bf16x8*)p.oWp)[(size_t)(sl*8 + ct*2 + kk)*64 + l] = w;
  }
  __syncthreads();

  // count src/dst membership in my 16-node window
  for (int i = tid; i < ecnt; i += 1024){
    int s = srcArr[ebase + i];
    if ((unsigned)(s - r0) < 16u) atomicAdd(&scnt[s - r0], 1);
    int d = dstArr[ebase + i];
    if ((unsigned)(d - r0) < 16u) atomicAdd(&dcnt[d - r0], 1);
  }
  __syncthreads();
  // prefix scans (wave0: src, wave1: dst)
  if (tid < 64){
    int v = (lane < 16) ? scnt[lane] : 0;
    int pre = v;
    #pragma unroll
    for (int off = 1; off < 16; off <<= 1){
      int u = __shfl_up(pre, off, 64);
      if (lane >= off) pre += u;
    }
    if (lane < 16){ sbase[lane] = pre - v; scur[lane] = pre - v; }
    if (lane == 15) sTot = pre;
  } else if (tid < 128){
    int v = (lane < 16) ? dcnt[lane] : 0;
    int pre = v;
    #pragma unroll
    for (int off = 1; off < 16; off <<= 1){
      int u = __shfl_up(pre, off, 64);
      if (lane >= off) pre += u;
    }
    if (lane < 16){ dbase[lane] = pre - v; dcur[lane] = pre - v; }
  }
  __syncthreads();
  // scatter local edge ids into src buckets (LDS+global) and dst buckets (global)
  for (int i = tid; i < ecnt; i += 1024){
    int s = srcArr[ebase + i];
    if ((unsigned)(s - r0) < 16u){
      int pos = atomicAdd(&scur[s - r0], 1);
      slist[pos] = (unsigned short)i;
      p.sbkt[(size_t)bid*2048 + pos] = (unsigned short)i;
    }
    int d = dstArr[ebase + i];
    if ((unsigned)(d - r0) < 16u){
      int pos = atomicAdd(&dcur[d - r0], 1);
      p.dbkt[(size_t)bid*2048 + pos] = (unsigned short)i;
    }
  }
  if (tid < 16){
    p.sbg[bid*16 + tid] = sbase[tid]; p.scg[bid*16 + tid] = scnt[tid];
    p.dbg[bid*16 + tid] = dbase[tid]; p.dcg[bid*16 + tid] = dcnt[tid];
  }

  // node embedding + LN0 -> albf (one node per wave, weights in LDS)
  {
    int nl = r0 + wid;
    const float* x = (side ? p.rec_x : p.lig_x) + (size_t)nl * nin;
    if (lane < nin) su.e.sx[wid][lane] = x[lane];
    float tv = p.nb[side][lane];
    for (int j = 0; j < nin; j++) tv += su.e.sx[wid][j] * su.e.nwl[j*64 + lane];
    su.e.st[wid][lane] = lrelu(tv);
    float hv = p.hb[side][lane];
    #pragma unroll 8
    for (int j = 0; j < 64; j++) hv += su.e.st[wid][j] * su.e.hwl[j*64 + lane];
    float m = wsum(hv) * (1.f/64.f);
    float d = hv - m;
    float v = wsum(d*d) * (1.f/64.f);
    float o = d * rsqrtf(v + 1e-5f) * p.g0[side][lane] + p.b0[side][lane];
    albf[wid][lane] = (__bf16)lrelu(o);
  }
  __syncthreads();   // slist + sTot + albf ready; emb LDS region now dead

  // edge embedding for OWNED edges (thread per edge) -> eh global
  {
    int total = sTot;
    const float* exb = side ? p.rec_e : p.lig_e;
    for (int t2 = tid; t2 < total; t2 += 1024){
      int el = slist[t2];
      const float* ex = exb + (size_t)(ebase + el) * 16;
      float x[16];
      #pragma unroll
      for (int j = 0; j < 16; j += 4){
        float4 v = *(const float4*)(ex + j);
        x[j] = v.x; x[j+1] = v.y; x[j+2] = v.z; x[j+3] = v.w;
      }
      float s[16];
      #pragma unroll
      for (int k = 0; k < 16; k++){
        float acc = sb[k];
        #pragma unroll
        for (int j = 0; j < 16; j++) acc += x[j] * sW[j*16 + k];
        s[k] = acc;
      }
      float* ehp = p.eh + (size_t)(egbase + el) * 16;
      #pragma unroll
      for (int k = 0; k < 16; k += 4)
        *(float4*)(ehp + k) = make_float4(s[k], s[k+1], s[k+2], s[k+3]);
    }
  }
  __threadfence_block();
  __syncthreads();

  // tmat layer 0: T = albf @ W_all, B-fragments gathered RAW from efW/efb
  {
    bf16x8 a0, a1;
    #pragma unroll
    for (int j = 0; j < 8; j++){
      a0[j] = albf[lane & 15][(lane >> 4)*8 + j];
      a1[j] = albf[lane & 15][32 + (lane >> 4)*8 + j];
    }
    const float* W0 = p.efW[side];   // layer 0 slice
    const float* B0 = p.efb[side];   // layer 0 bias
    int orow = (lane >> 4)*4, ocol = lane & 15;
    for (int ct = wid; ct < 68; ct += 16){
      int oc = ct*16 + ocol;
      int kslot = oc >> 6, oo = oc & 63;
      const float* src = (kslot < 16) ? (W0 + (size_t)kslot*4096) : B0;
      bf16x8 b0, b1;
      #pragma unroll
      for (int j = 0; j < 8; j++){
        int i0 = (lane >> 4)*8 + j;
        b0[j] = (__bf16)src[(size_t)i0*64 + oo];
        b1[j] = (__bf16)src[(size_t)(32 + i0)*64 + oo];
      }
      f32x4 d = {0.f, 0.f, 0.f, 0.f};
      d = __builtin_amdgcn_mfma_f32_16x16x32_bf16(a0, b0, d, 0, 0, 0);
      d = __builtin_amdgcn_mfma_f32_16x16x32_bf16(a1, b1, d, 0, 0, 0);
      int col = ct*16 + ocol;
      su.Tl[orow+0][col] = (__bf16)d[0];
      su.Tl[orow+1][col] = (__bf16)d[1];
      su.Tl[orow+2][col] = (__bf16)d[2];
      su.Tl[orow+3][col] = (__bf16)d[3];
    }
  }
  __syncthreads();

  // msg layer 0: one src per wave -> msgvA (dense per-edge store, no atomics)
  {
    int cnt = scnt[wid];
    if (cnt > 0){
      float t[17];
      #pragma unroll
      for (int k = 0; k < 17; k++) t[k] = (float)su.Tl[wid][k*64 + lane];
      int base = sbase[wid];
      auto doe = [&](int el){
        const float4* ehp = (const float4*)(p.eh + (size_t)(egbase + el)*16);
        float4 v0 = ehp[0], v1 = ehp[1], v2 = ehp[2], v3 = ehp[3];
        float m = t[16];
        m += v0.x*t[0]  + v0.y*t[1]  + v0.z*t[2]  + v0.w*t[3];
        m += v1.x*t[4]  + v1.y*t[5]  + v1.z*t[6]  + v1.w*t[7];
        m += v2.x*t[8]  + v2.y*t[9]  + v2.z*t[10] + v2.w*t[11];
        m += v3.x*t[12] + v3.y*t[13] + v3.z*t[14] + v3.w*t[15];
        p.msgvA[(size_t)(egbase + el)*64 + lane] = m;
      };
      int i = 0;
      for (; i + 2 <= cnt; i += 2){ doe(slist[base+i]); doe(slist[base+i+1]); }
      if (i < cnt) doe(slist[base+i]);
    }
  }
}

// ---- K_mid (320 x 1024): upd(l-1) via msgv gather -> tmat(packed) -> msg ----
__global__ __launch_bounds__(1024, 8) void k_mid(Params p, int layer){
  const int tid = threadIdx.x, bid = blockIdx.x;
  const int lane = tid & 63, wid = tid >> 6;
  int side, r0, gr0, ebase, ecnt, egbase;
  const int *srcArr, *dstArr;
  window(bid, side, r0, gr0, ebase, ecnt, egbase, srcArr, dstArr, p);
  const float* mi = (layer == 1) ? p.msgvA : p.msgvB;
  float*       mo = (layer == 1) ? p.msgvB : p.msgvA;

  __shared__ __bf16 Tl[16][TPAD];
  __shared__ __bf16 albf[16][64];
  __shared__ __bf16 sabf[16][64];
  __shared__ float updo[16][68];

  // upd(layer-1): gather in-edge messages, /deg + convb, lrelu
  {
    int lm1 = layer - 1;
    int cnt  = p.dcg[bid*16 + wid];
    int base = p.dbg[bid*16 + wid];
    const unsigned short* dl = p.dbkt + (size_t)bid*2048 + base;
    float acc = 0.f;
    int i = 0;
    for (; i + 4 <= cnt; i += 4){
      int e0 = dl[i], e1 = dl[i+1], e2 = dl[i+2], e3 = dl[i+3];
      float x0 = mi[(size_t)(egbase + e0)*64 + lane];
      float x1 = mi[(size_t)(egbase + e1)*64 + lane];
      float x2 = mi[(size_t)(egbase + e2)*64 + lane];
      float x3 = mi[(size_t)(egbase + e3)*64 + lane];
      acc += (x0 + x1) + (x2 + x3);
    }
    for (; i < cnt; i++) acc += mi[(size_t)(egbase + dl[i])*64 + lane];
    float dg = fmaxf((float)cnt, 1.f);
    float a = lrelu(acc / dg + p.convb[side][lm1*64 + lane]);
    sabf[wid][lane] = (__bf16)a;
    __syncthreads();
    if (wid < 4){
      int ct = wid;
      bf16x8 a0u, a1u;
      #pragma unroll
      for (int j = 0; j < 8; j++){
        a0u[j] = sabf[lane & 15][(lane >> 4)*8 + j];
        a1u[j] = sabf[lane & 15][32 + (lane >> 4)*8 + j];
      }
      const bf16x8* Ob = (const bf16x8*)p.oWp + (size_t)(side*3 + lm1)*8*64;
      bf16x8 b0 = Ob[(ct*2 + 0)*64 + lane];
      bf16x8 b1 = Ob[(ct*2 + 1)*64 + lane];
      f32x4 d = {0.f, 0.f, 0.f, 0.f};
      d = __builtin_amdgcn_mfma_f32_16x16x32_bf16(a0u, b0, d, 0, 0, 0);
      d = __builtin_amdgcn_mfma_f32_16x16x32_bf16(a1u, b1, d, 0, 0, 0);
      int orw = (lane >> 4)*4, ocl = ct*16 + (lane & 15);
      updo[orw+0][ocl] = d[0];
      updo[orw+1][ocl] = d[1];
      updo[orw+2][ocl] = d[2];
      updo[orw+3][ocl] = d[3];
    }
    __syncthreads();
    {
      float hv = p.outb[side][lm1*64 + lane] + updo[wid][lane];
      float m = wsum(hv) * (1.f/64.f);
      float d = hv - m;
      float v = wsum(d*d) * (1.f/64.f);
      float o = d * rsqrtf(v + 1e-5f) * p.lng[side][lm1*64 + lane] + p.lnb[side][lm1*64 + lane];
      if (layer == 1) p.prev0[(size_t)(gr0 + wid)*64 + lane] = o;  // h after layer 0
      albf[wid][lane] = (__bf16)lrelu(o);
    }
  }
  __syncthreads();

  // tmat: packed Wp, software-pipelined
  {
    bf16x8 a0, a1;
    #pragma unroll
    for (int j = 0; j < 8; j++){
      a0[j] = albf[lane & 15][(lane >> 4)*8 + j];
      a1[j] = albf[lane & 15][32 + (lane >> 4)*8 + j];
    }
    const bf16x8* Wb = (const bf16x8*)p.Wp + (size_t)(side*3 + layer)*68*2*64;
    int orow = (lane >> 4)*4, ocol = lane & 15;
    int ct = wid;
    bf16x8 b0 = Wb[(ct*2 + 0)*64 + lane];
    bf16x8 b1 = Wb[(ct*2 + 1)*64 + lane];
    while (ct < 68){
      int ctn = ct + 16;
      bf16x8 nb0 = b0, nb1 = b1;
      if (ctn < 68){ nb0 = Wb[(ctn*2 + 0)*64 + lane]; nb1 = Wb[(ctn*2 + 1)*64 + lane]; }
      f32x4 d = {0.f, 0.f, 0.f, 0.f};
      d = __builtin_amdgcn_mfma_f32_16x16x32_bf16(a0, b0, d, 0, 0, 0);
      d = __builtin_amdgcn_mfma_f32_16x16x32_bf16(a1, b1, d, 0, 0, 0);
      int col = ct*16 + ocol;
      Tl[orow+0][col] = (__bf16)d[0];
      Tl[orow+1][col] = (__bf16)d[1];
      Tl[orow+2][col] = (__bf16)d[2];
      Tl[orow+3][col] = (__bf16)d[3];
      b0 = nb0; b1 = nb1; ct = ctn;
    }
  }
  __syncthreads();

  // msg: one src per wave -> msgv out (dense store)
  {
    int cnt  = p.scg[bid*16 + wid];
    if (cnt > 0){
      float t[17];
      #pragma unroll
      for (int k = 0; k < 17; k++) t[k] = (float)Tl[wid][k*64 + lane];
      const unsigned short* sl = p.sbkt + (size_t)bid*2048 + p.sbg[bid*16 + wid];
      auto doe = [&](int el){
        const float4* ehp = (const float4*)(p.eh + (size_t)(egbase + el)*16);
        float4 v0 = ehp[0], v1 = ehp[1], v2 = ehp[2], v3 = ehp[3];
        float m = t[16];
        m += v0.x*t[0]  + v0.y*t[1]  + v0.z*t[2]  + v0.w*t[3];
        m += v1.x*t[4]  + v1.y*t[5]  + v1.z*t[6]  + v1.w*t[7];
        m += v2.x*t[8]  + v2.y*t[9]  + v2.z*t[10] + v2.w*t[11];
        m += v3.x*t[12] + v3.y*t[13] + v3.z*t[14] + v3.w*t[15];
        mo[(size_t)(egbase + el)*64 + lane] = m;
      };
      int i = 0;
      for (; i + 2 <= cnt; i += 2){ doe(sl[i]); doe(sl[i+1]); }
      if (i < cnt) doe(sl[i]);
    }
  }
}

// ---- K_back (256 x 1024): upd(2) via gather + residual + score --------------
__global__ __launch_bounds__(1024) void k_back(Params p){
  const int tid = threadIdx.x, bid = blockIdx.x;
  const int lane = tid & 63, wid = tid >> 6;
  int b = bid >> 4, rt = bid & 15;
  __shared__ float slh[64][65];
  __shared__ float srh[16][65];
  __shared__ float owl[2][4096];
  __shared__ float sa[16][64];
  __shared__ float ps[16];

  for (int idx = tid; idx < 4096; idx += 1024){
    owl[0][idx] = p.outW[0][2*4096 + idx];
    owl[1][idx] = p.outW[1][2*4096 + idx];
  }
  __syncthreads();

  // upd_2 for 64 lig rows of batch b + my 16 rec rows (5 rows per wave)
  for (int rr = wid; rr < 80; rr += 16){
    int side = rr >= 64;
    int n, wbid, loc, egb;
    if (!side){ n = b*64 + rr;                      wbid = b*4 + (rr >> 4); loc = rr & 15;  egb = b*512; }
    else      { n = NLIG + b*256 + rt*16 + (rr-64); wbid = 64 + b*16 + rt;  loc = rr - 64;  egb = ELIG + b*2048; }
    int cnt  = p.dcg[wbid*16 + loc];
    int base = p.dbg[wbid*16 + loc];
    const unsigned short* dl = p.dbkt + (size_t)wbid*2048 + base;
    float acc = 0.f;
    int i = 0;
    for (; i + 4 <= cnt; i += 4){
      int e0 = dl[i], e1 = dl[i+1], e2 = dl[i+2], e3 = dl[i+3];
      float x0 = p.msgvA[(size_t)(egb + e0)*64 + lane];
      float x1 = p.msgvA[(size_t)(egb + e1)*64 + lane];
      float x2 = p.msgvA[(size_t)(egb + e2)*64 + lane];
      float x3 = p.msgvA[(size_t)(egb + e3)*64 + lane];
      acc += (x0 + x1) + (x2 + x3);
    }
    for (; i < cnt; i++) acc += p.msgvA[(size_t)(egb + dl[i])*64 + lane];
    float dg = fmaxf((float)cnt, 1.f);
    float a = lrelu(acc / dg + p.convb[side][128 + lane]);
    sa[wid][lane] = a;
    float hv = p.outb[side][128 + lane];
    const float* ow = &owl[side][0];
    #pragma unroll 8
    for (int j = 0; j < 64; j++) hv += sa[wid][j] * ow[j*64 + lane];
    float m = wsum(hv) * (1.f/64.f);
    float d = hv - m;
    float v = wsum(d*d) * (1.f/64.f);
    float o = d * rsqrtf(v + 1e-5f) * p.lng[side][128 + lane] + p.lnb[side][128 + lane];
    o += p.prev0[(size_t)n*64 + lane];     // residual: + h after layer 0
    if (side) srh[rr - 64][lane] = o; else slh[rr][lane] = o;
  }
  __syncthreads();

  // score: each thread owns one (lig row, rec col) pair
  int r = tid & 15, lg = tid >> 4;
  float acc = 0.f;
  #pragma unroll 8
  for (int f = 0; f < 64; f++) acc += slh[lg][f] * srh[r][f];
  p.out[16 + (size_t)b*16384 + (size_t)lg*256 + rt*16 + r] = acc;

  float psum = wsum(acc);
  if (lane == 0) ps[wid] = psum;
  __syncthreads();
  if (tid == 0){
    float s = 0.f;
    #pragma unroll
    for (int i = 0; i < 16; i++) s += ps[i];
    atomicAdd(&p.out[b], s * (1.f/16384.f));
  }
}

extern "C" void kernel_launch(void* const* d_in, const int* in_sizes, int n_in,
                              void* d_out, int out_size, void* d_ws, size_t ws_size,
                              hipStream_t stream){
  Params p;
  p.lig_x  = (const float*)d_in[0];
  p.rec_x  = (const float*)d_in[1];
  p.lig_e  = (const float*)d_in[2];
  p.rec_e  = (const float*)d_in[3];
  p.lig_src = (const int*)d_in[4];
  p.lig_dst = (const int*)d_in[5];
  p.rec_src = (const int*)d_in[6];
  p.rec_dst = (const int*)d_in[7];
  for (int s = 0; s < 2; s++){
    const int o = 8 + s*15;
    p.nW[s]   = (const float*)d_in[o+0];  p.nb[s]   = (const float*)d_in[o+1];
    p.eW[s]   = (const float*)d_in[o+2];  p.eb[s]   = (const float*)d_in[o+3];
    p.hW[s]   = (const float*)d_in[o+4];  p.hb[s]   = (const float*)d_in[o+5];
    p.g0[s]   = (const float*)d_in[o+6];  p.b0[s]   = (const float*)d_in[o+7];
    p.efW[s]  = (const float*)d_in[o+8];  p.efb[s]  = (const float*)d_in[o+9];
    p.convb[s]= (const float*)d_in[o+10]; p.outW[s] = (const float*)d_in[o+11];
    p.outb[s] = (const float*)d_in[o+12]; p.lng[s]  = (const float*)d_in[o+13];
    p.lnb[s]  = (const float*)d_in[o+14];
  }
  char* W = (char*)d_ws;
  p.msgvA = (float*)W;  W += (size_t)ETOT*64*4;
  p.msgvB = (float*)W;  W += (size_t)ETOT*64*4;
  p.prev0 = (float*)W;  W += (size_t)NTOT*64*4;
  p.eh    = (float*)W;  W += (size_t)ETOT*16*4;
  p.Wp    = (__bf16*)W; W += (size_t)2*3*68*2*64*8*2;
  p.oWp   = (__bf16*)W; W += (size_t)2*3*4*2*64*8*2;
  p.sbg   = (int*)W;    W += (size_t)320*16*4;
  p.scg   = (int*)W;    W += (size_t)320*16*4;
  p.dbg   = (int*)W;    W += (size_t)320*16*4;
  p.dcg   = (int*)W;    W += (size_t)320*16*4;
  p.sbkt  = (unsigned short*)W; W += (size_t)320*2048*2;
  p.dbkt  = (unsigned short*)W; W += (size_t)320*2048*2;
  p.out   = (float*)d_out;

  k_front<<<320, 1024, 0, stream>>>(p);
  k_mid<<<320, 1024, 0, stream>>>(p, 1);
  k_mid<<<320, 1024, 0, stream>>>(p, 2);
  k_back<<<256, 1024, 0, stream>>>(p);
}

// Round 11
// 95.217 us; speedup vs baseline: 1.3975x; 1.3975x over previous
//
#include <hip/hip_runtime.h>
#include <hip/hip_bf16.h>

#define NLIG 1024
#define NREC 4096
#define NTOT 5120
#define ELIG 8192
#define ETOT 40960
#define TPAD 1092      // 17*64 padded +4

typedef __bf16 bf16x8 __attribute__((ext_vector_type(8)));
typedef float f32x4 __attribute__((ext_vector_type(4)));

struct Params {
  const float *lig_x, *rec_x, *lig_e, *rec_e;
  const int *lig_src, *lig_dst, *rec_src, *rec_dst;
  const float *nW[2], *nb[2], *eW[2], *eb[2], *hW[2], *hb[2], *g0[2], *b0[2];
  const float *efW[2], *efb[2], *convb[2], *outW[2], *outb[2], *lng[2], *lnb[2];
  float *aggA, *aggB, *prev0;
  __bf16 *eh, *Abf, *Wp, *oWp;
  int *deg;
  unsigned *bkt;          // [320][2048] (dst<<16)|local_eid, bucketed by src
  int *bktbase, *bktcnt;  // [320][16]
  float *out;
};

__device__ __forceinline__ float lrelu(float v){ return v > 0.f ? v : 0.01f * v; }

__device__ __forceinline__ float wsum(float v){
  #pragma unroll
  for (int off = 32; off > 0; off >>= 1) v += __shfl_xor(v, off, 64);
  return v;
}

// Window decomposition: block -> 16 nodes of one graph + that graph's edge range.
__device__ __forceinline__ void window(int bid, int& side, int& r0, int& gr0,
                                       int& ebase, int& ecnt, int& egbase,
                                       const int*& srcArr, const int*& dstArr,
                                       const Params& p){
  if (bid < 64){
    side = 0; int b = bid >> 2, w = bid & 3;
    r0 = b*64 + w*16; gr0 = r0; ebase = b*512; ecnt = 512; egbase = ebase;
    srcArr = p.lig_src; dstArr = p.lig_dst;
  } else {
    side = 1; int g = bid - 64; int b = g >> 4, w = g & 15;
    r0 = b*256 + w*16; gr0 = NLIG + r0; ebase = b*2048; ecnt = 2048; egbase = ELIG + ebase;
    srcArr = p.rec_src; dstArr = p.rec_dst;
  }
}

// ---- K_pre (320 x 1024): prepW+prep-outW + edge emb(bf16) + LN0->Abf
//      + zero + per-window src-bucketing + deg --------------------------------
__global__ __launch_bounds__(1024) void k_pre(Params p){
  __shared__ float sW[2][256], sb[2][16];
  __shared__ float nwl[40*64];          // my side's emb_nW (LDS-staged)
  __shared__ float hwl[64*64];          // my side's hidW
  __shared__ float sx[16][40], st[16][64];
  __shared__ int scnt[16], sbase[16], scur[16], dcnt[16];
  const int tid = threadIdx.x, bid = blockIdx.x;
  const int lane = tid & 63, wid = tid >> 6;
  const int gtid = bid*1024 + tid;

  int side, r0, gr0, ebase, ecnt, egbase;
  const int *srcArr, *dstArr;
  window(bid, side, r0, gr0, ebase, ecnt, egbase, srcArr, dstArr, p);
  const int nin = side ? 40 : 32;

  if (tid < 256){ sW[0][tid] = p.eW[0][tid]; sW[1][tid] = p.eW[1][tid]; }
  if (tid < 16){ sb[0][tid] = p.eb[0][tid]; sb[1][tid] = p.eb[1][tid];
                 scnt[tid] = 0; dcnt[tid] = 0; }
  for (int i = tid; i < nin*64; i += 1024) nwl[i] = p.nW[side][i];
  for (int i = tid; i < 4096; i += 1024) hwl[i] = p.hW[side][i];
  __syncthreads();

  // pack W_all = [efW 0..15 | efb] into MFMA B-fragment order
  if (gtid < 52224){
    int l  = gtid & 63;
    int t2 = gtid >> 6;
    int kk = t2 & 1;
    int t3 = t2 >> 1;
    int ct = t3 % 68;
    int sl = t3 / 68;            // side*3 + layer
    int sd = sl / 3, ly = sl % 3;
    int ocol = ct*16 + (l & 15);
    int kslot = ocol >> 6, oo = ocol & 63;
    const float* src = (kslot < 16)
        ? (p.efW[sd] + (size_t)ly*16*4096 + (size_t)kslot*4096)
        : (p.efb[sd] + (size_t)ly*4096);
    bf16x8 w;
    #pragma unroll
    for (int j = 0; j < 8; j++){
      int i = kk*32 + (l >> 4)*8 + j;
      w[j] = (__bf16)src[i*64 + oo];
    }
    ((bf16x8*)p.Wp)[(size_t)sl*68*2*64 + (ct*2 + kk)*64 + l] = w;
  } else if (gtid < 52224 + 3072){
    // pack outW (3 layers x 2 sides, 64x64) into B-fragment order
    int id2 = gtid - 52224;
    int l = id2 & 63;
    int t2 = id2 >> 6;
    int kk = t2 & 1;
    int ct = (t2 >> 1) & 3;
    int sl = t2 >> 3;            // side*3 + layer (0..5)
    int sd = sl / 3, ly = sl % 3;
    const float* src = p.outW[sd] + (size_t)ly*4096;
    bf16x8 w;
    #pragma unroll
    for (int j = 0; j < 8; j++){
      int i = kk*32 + (l >> 4)*8 + j;
      w[j] = (__bf16)src[i*64 + ct*16 + (l & 15)];
    }
    ((bf16x8*)p.oWp)[(size_t)(sl*8 + ct*2 + kk)*64 + l] = w;
  }

  // edge embedding -> eh (bf16)
  if (gtid < ETOT){
    int e = gtid;
    int esd = e >= ELIG;
    int el = esd ? e - ELIG : e;
    const float* ex = (esd ? p.rec_e : p.lig_e) + (size_t)el * 16;
    float x[16];
    #pragma unroll
    for (int j = 0; j < 16; j += 4){
      float4 v = *(const float4*)(ex + j);
      x[j] = v.x; x[j+1] = v.y; x[j+2] = v.z; x[j+3] = v.w;
    }
    bf16x8 s0, s1;
    #pragma unroll
    for (int k = 0; k < 16; k++){
      float acc = sb[esd][k];
      #pragma unroll
      for (int j = 0; j < 16; j++) acc += x[j] * sW[esd][j*16 + k];
      if (k < 8) s0[k] = (__bf16)acc; else s1[k-8] = (__bf16)acc;
    }
    bf16x8* ehp = (bf16x8*)(p.eh + (size_t)e * 16);
    ehp[0] = s0; ehp[1] = s1;
  }

  // zero both agg buffers + out[0..15]
  for (int i = gtid; i < NTOT*64; i += 320*1024){ p.aggA[i] = 0.f; p.aggB[i] = 0.f; }
  if (gtid < 16) p.out[gtid] = 0.f;

  // node embedding + LN0 -> Abf : one node per wave, weights from LDS
  {
    int n = gr0 + wid;
    int nl = r0 + wid;
    const float* x = (side ? p.rec_x : p.lig_x) + (size_t)nl * nin;
    if (lane < nin) sx[wid][lane] = x[lane];
    float tv = p.nb[side][lane];
    for (int j = 0; j < nin; j++) tv += sx[wid][j] * nwl[j*64 + lane];
    st[wid][lane] = lrelu(tv);
    float hv = p.hb[side][lane];
    #pragma unroll 8
    for (int j = 0; j < 64; j++) hv += st[wid][j] * hwl[j*64 + lane];
    float m = wsum(hv) * (1.f/64.f);
    float d = hv - m;
    float v = wsum(d*d) * (1.f/64.f);
    float o = d * rsqrtf(v + 1e-5f) * p.g0[side][lane] + p.b0[side][lane];
    p.Abf[(size_t)n*64 + lane] = (__bf16)lrelu(o);
  }

  // bucketing (layer-invariant): count
  for (int i = tid; i < ecnt; i += 1024){
    int s = srcArr[ebase + i];
    if ((unsigned)(s - r0) < 16u) atomicAdd(&scnt[s - r0], 1);
    int d = dstArr[ebase + i];
    if ((unsigned)(d - r0) < 16u) atomicAdd(&dcnt[d - r0], 1);
  }
  __syncthreads();
  if (tid < 64){
    int v = (lane < 16) ? scnt[lane] : 0;
    int pre = v;
    #pragma unroll
    for (int off = 1; off < 16; off <<= 1){
      int u = __shfl_up(pre, off, 64);
      if (lane >= off) pre += u;
    }
    if (lane < 16){ sbase[lane] = pre - v; scur[lane] = pre - v; }
  }
  if (tid < 16) p.deg[gr0 + tid] = dcnt[tid];
  __syncthreads();
  for (int i = tid; i < ecnt; i += 1024){
    int s = srcArr[ebase + i];
    if ((unsigned)(s - r0) < 16u){
      int d = dstArr[ebase + i];
      int pos = atomicAdd(&scur[s - r0], 1);
      p.bkt[(size_t)bid*2048 + pos] = ((unsigned)d << 16) | (unsigned)i;
    }
  }
  if (tid < 16){ p.bktbase[bid*16 + tid] = sbase[tid]; p.bktcnt[bid*16 + tid] = scnt[tid]; }
}

// ---- K_layer (320 x 1024, 2 blocks/CU): upd(l-1,MFMA) -> tmat(pipelined) -> msg
__global__ __launch_bounds__(1024, 8) void k_layer(Params p, int layer){
  const int tid = threadIdx.x, bid = blockIdx.x;
  const int lane = tid & 63, wid = tid >> 6;        // wid 0..15
  int side, r0, gr0, ebase, ecnt, egbase;
  const int *srcArr, *dstArr;
  window(bid, side, r0, gr0, ebase, ecnt, egbase, srcArr, dstArr, p);
  float* aggR = (layer == 1) ? p.aggA : p.aggB;   // read by upd (layer-1)
  float* aggW = (layer == 1) ? p.aggB : p.aggA;   // written by msg (layer)

  // hoisted scalar metadata (overlaps with upd phase)
  const int myDeg  = p.deg[gr0 + wid];
  const int myCnt  = p.bktcnt[bid*16 + wid];
  const int myBase = p.bktbase[bid*16 + wid];

  __shared__ __bf16 Tl[16][TPAD];          // 34.9 KB
  __shared__ __bf16 albf[16][64];          // 2 KB
  __shared__ __bf16 sabf[16][64];          // 2 KB
  __shared__ float updo[16][68];           // 4.35 KB (MFMA C, padded)

  // upd(layer-1): lrelu(agg/deg+convb) -> MFMA @outW -> LN -> albf
  if (layer > 0){
    int lm1 = layer - 1;
    int n = gr0 + wid;
    float a = aggR[(size_t)n*64 + lane];
    aggR[(size_t)n*64 + lane] = 0.f;       // ping-pong re-zero for layer+1
    float dg = fmaxf((float)myDeg, 1.f);
    a = lrelu(a / dg + p.convb[side][lm1*64 + lane]);
    sabf[wid][lane] = (__bf16)a;
    __syncthreads();
    if (wid < 4){
      int ct = wid;
      bf16x8 a0u, a1u;
      #pragma unroll
      for (int j = 0; j < 8; j++){
        a0u[j] = sabf[lane & 15][(lane >> 4)*8 + j];
        a1u[j] = sabf[lane & 15][32 + (lane >> 4)*8 + j];
      }
      const bf16x8* Ob = (const bf16x8*)p.oWp + (size_t)(side*3 + lm1)*8*64;
      bf16x8 b0 = Ob[(ct*2 + 0)*64 + lane];
      bf16x8 b1 = Ob[(ct*2 + 1)*64 + lane];
      f32x4 d = {0.f, 0.f, 0.f, 0.f};
      d = __builtin_amdgcn_mfma_f32_16x16x32_bf16(a0u, b0, d, 0, 0, 0);
      d = __builtin_amdgcn_mfma_f32_16x16x32_bf16(a1u, b1, d, 0, 0, 0);
      int orw = (lane >> 4)*4, ocl = ct*16 + (lane & 15);
      updo[orw+0][ocl] = d[0];
      updo[orw+1][ocl] = d[1];
      updo[orw+2][ocl] = d[2];
      updo[orw+3][ocl] = d[3];
    }
    __syncthreads();
    {
      float hv = p.outb[side][lm1*64 + lane] + updo[wid][lane];
      float m = wsum(hv) * (1.f/64.f);
      float d = hv - m;
      float v = wsum(d*d) * (1.f/64.f);
      float o = d * rsqrtf(v + 1e-5f) * p.lng[side][lm1*64 + lane] + p.lnb[side][lm1*64 + lane];
      if (layer == 1) p.prev0[(size_t)n*64 + lane] = o;   // h after layer 0 (residual)
      albf[wid][lane] = (__bf16)lrelu(o);
    }
  }
  __syncthreads();

  // tmat: T[16][1088] = lrelu(h) @ W_all into LDS; Wb loads software-pipelined
  bf16x8 a0, a1;
  if (layer == 0){
    const bf16x8* A = (const bf16x8*)(p.Abf + (size_t)(gr0 + (lane & 15))*64 + (lane >> 4)*8);
    a0 = A[0]; a1 = A[4];
  } else {
    #pragma unroll
    for (int j = 0; j < 8; j++){
      a0[j] = albf[lane & 15][(lane >> 4)*8 + j];
      a1[j] = albf[lane & 15][32 + (lane >> 4)*8 + j];
    }
  }
  const bf16x8* Wb = (const bf16x8*)p.Wp + (size_t)(side*3 + layer)*68*2*64;
  int orow = (lane >> 4)*4, ocol = lane & 15;
  {
    int ct = wid;
    bf16x8 b0 = Wb[(ct*2 + 0)*64 + lane];
    bf16x8 b1 = Wb[(ct*2 + 1)*64 + lane];
    while (ct < 68){
      int ctn = ct + 16;
      bf16x8 nb0 = b0, nb1 = b1;
      if (ctn < 68){ nb0 = Wb[(ctn*2 + 0)*64 + lane]; nb1 = Wb[(ctn*2 + 1)*64 + lane]; }
      f32x4 d = {0.f, 0.f, 0.f, 0.f};
      d = __builtin_amdgcn_mfma_f32_16x16x32_bf16(a0, b0, d, 0, 0, 0);
      d = __builtin_amdgcn_mfma_f32_16x16x32_bf16(a1, b1, d, 0, 0, 0);
      int col = ct*16 + ocol;
      Tl[orow+0][col] = (__bf16)d[0];
      Tl[orow+1][col] = (__bf16)d[1];
      Tl[orow+2][col] = (__bf16)d[2];
      Tl[orow+3][col] = (__bf16)d[3];
      b0 = nb0; b1 = nb1; ct = ctn;
    }
  }
  __syncthreads();

  // msg: one src per wave; T row in regs; bf16 eh rows; 4 edges in flight
  if (myCnt > 0){
    float t[17];
    #pragma unroll
    for (int k = 0; k < 17; k++) t[k] = (float)Tl[wid][k*64 + lane];
    size_t base = (size_t)bid*2048 + myBase;
    for (int c0 = 0; c0 < myCnt; c0 += 64){
      int nn = min(64, myCnt - c0);
      unsigned ew = (lane < nn) ? p.bkt[base + c0 + lane] : 0u;
      auto doe = [&](unsigned v, bf16x8 e0, bf16x8 e1){
        int gd = (int)(v >> 16) + (side ? NLIG : 0);
        float m = t[16];
        #pragma unroll
        for (int k = 0; k < 8; k++) m += (float)e0[k] * t[k];
        #pragma unroll
        for (int k = 0; k < 8; k++) m += (float)e1[k] * t[8+k];
        atomicAdd(&aggW[(size_t)gd*64 + lane], m);
      };
      auto rowp = [&](unsigned v){
        return (const bf16x8*)(p.eh + (size_t)(egbase + (int)(v & 0xffffu))*16);
      };
      int j = 0;
      for (; j + 4 <= nn; j += 4){
        unsigned v0 = __shfl(ew, j, 64),   v1 = __shfl(ew, j+1, 64);
        unsigned v2 = __shfl(ew, j+2, 64), v3 = __shfl(ew, j+3, 64);
        const bf16x8 *p0 = rowp(v0), *p1 = rowp(v1), *p2 = rowp(v2), *p3 = rowp(v3);
        bf16x8 a0e = p0[0], a1e = p0[1], b0e = p1[0], b1e = p1[1];
        bf16x8 c0e = p2[0], c1e = p2[1], d0e = p3[0], d1e = p3[1];
        doe(v0, a0e, a1e); doe(v1, b0e, b1e); doe(v2, c0e, c1e); doe(v3, d0e, d1e);
      }
      for (; j < nn; j++){
        unsigned v0 = __shfl(ew, j, 64);
        const bf16x8* pp = rowp(v0);
        doe(v0, pp[0], pp[1]);
      }
    }
  }
}

// ---- K_final: upd(2) into LDS + score (1024 threads) ------------------------
__global__ __launch_bounds__(1024) void k_final(Params p){
  const int tid = threadIdx.x, bid = blockIdx.x;
  const int lane = tid & 63, wid = tid >> 6;       // wid 0..15
  int b = bid >> 4, rt = bid & 15;
  __shared__ float slh[64][65];
  __shared__ float srh[16][65];
  __shared__ float owl[2][4096];
  __shared__ float sa[16][64];
  __shared__ float ps[16];

  for (int idx = tid; idx < 4096; idx += 1024){
    owl[0][idx] = p.outW[0][2*4096 + idx];
    owl[1][idx] = p.outW[1][2*4096 + idx];
  }
  __syncthreads();

  // upd_2 for 64 lig rows of batch b + my 16 rec rows (5 rows per wave)
  for (int rr = wid; rr < 80; rr += 16){
    int side = rr >= 64;
    int n = side ? (NLIG + b*256 + rt*16 + (rr - 64)) : (b*64 + rr);
    float a = p.aggA[(size_t)n*64 + lane];
    float dg = fmaxf((float)p.deg[n], 1.f);
    a = lrelu(a / dg + p.convb[side][128 + lane]);
    sa[wid][lane] = a;
    float hv = p.outb[side][128 + lane];
    const float* ow = &owl[side][0];
    #pragma unroll 8
    for (int j = 0; j < 64; j++) hv += sa[wid][j] * ow[j*64 + lane];
    float m = wsum(hv) * (1.f/64.f);
    float d = hv - m;
    float v = wsum(d*d) * (1.f/64.f);
    float o = d * rsqrtf(v + 1e-5f) * p.lng[side][128 + lane] + p.lnb[side][128 + lane];
    o += p.prev0[(size_t)n*64 + lane];     // residual: + h after layer 0
    if (side) srh[rr - 64][lane] = o; else slh[rr][lane] = o;
  }
  __syncthreads();

  // score: each thread owns one (lig row, rec col) pair
  int r = tid & 15, lg = tid >> 4;         // r 0..15, lg 0..63
  float acc = 0.f;
  #pragma unroll 8
  for (int f = 0; f < 64; f++) acc += slh[lg][f] * srh[r][f];
  p.out[16 + (size_t)b*16384 + (size_t)lg*256 + rt*16 + r] = acc;

  float psum = wsum(acc);
  if (lane == 0) ps[wid] = psum;
  __syncthreads();
  if (tid == 0){
    float s = 0.f;
    #pragma unroll
    for (int i = 0; i < 16; i++) s += ps[i];
    atomicAdd(&p.out[b], s * (1.f/16384.f));
  }
}

extern "C" void kernel_launch(void* const* d_in, const int* in_sizes, int n_in,
                              void* d_out, int out_size, void* d_ws, size_t ws_size,
                              hipStream_t stream){
  Params p;
  p.lig_x  = (const float*)d_in[0];
  p.rec_x  = (const float*)d_in[1];
  p.lig_e  = (const float*)d_in[2];
  p.rec_e  = (const float*)d_in[3];
  p.lig_src = (const int*)d_in[4];
  p.lig_dst = (const int*)d_in[5];
  p.rec_src = (const int*)d_in[6];
  p.rec_dst = (const int*)d_in[7];
  for (int s = 0; s < 2; s++){
    const int o = 8 + s*15;
    p.nW[s]   = (const float*)d_in[o+0];  p.nb[s]   = (const float*)d_in[o+1];
    p.eW[s]   = (const float*)d_in[o+2];  p.eb[s]   = (const float*)d_in[o+3];
    p.hW[s]   = (const float*)d_in[o+4];  p.hb[s]   = (const float*)d_in[o+5];
    p.g0[s]   = (const float*)d_in[o+6];  p.b0[s]   = (const float*)d_in[o+7];
    p.efW[s]  = (const float*)d_in[o+8];  p.efb[s]  = (const float*)d_in[o+9];
    p.convb[s]= (const float*)d_in[o+10]; p.outW[s] = (const float*)d_in[o+11];
    p.outb[s] = (const float*)d_in[o+12]; p.lng[s]  = (const float*)d_in[o+13];
    p.lnb[s]  = (const float*)d_in[o+14];
  }
  char* W = (char*)d_ws;
  p.aggA  = (float*)W;  W += (size_t)NTOT*64*4;
  p.aggB  = (float*)W;  W += (size_t)NTOT*64*4;
  p.prev0 = (float*)W;  W += (size_t)NTOT*64*4;
  p.eh    = (__bf16*)W; W += (size_t)ETOT*16*2;
  p.Abf   = (__bf16*)W; W += (size_t)NTOT*64*2;
  p.Wp    = (__bf16*)W; W += (size_t)2*3*68*2*64*8*2;
  p.oWp   = (__bf16*)W; W += (size_t)2*3*4*2*64*8*2;
  p.deg   = (int*)W;    W += (size_t)NTOT*4;
  p.bkt   = (unsigned*)W; W += (size_t)320*2048*4;
  p.bktbase = (int*)W;  W += (size_t)320*16*4;
  p.bktcnt  = (int*)W;  W += (size_t)320*16*4;
  p.out   = (float*)d_out;

  k_pre<<<320, 1024, 0, stream>>>(p);
  k_layer<<<320, 1024, 0, stream>>>(p, 0);
  k_layer<<<320, 1024, 0, stream>>>(p, 1);
  k_layer<<<320, 1024, 0, stream>>>(p, 2);
  k_final<<<256, 1024, 0, stream>>>(p);
}